// Round 4
// baseline (234.208 us; speedup 1.0000x reference)
//
#include <hip/hip_runtime.h>
#include <hip/hip_bf16.h>
#include <stdint.h>

#define B_SZ 8192
#define D_SZ 512
#define U_SZ 512
#define M_SZ 16
#define K_SZ 64

typedef short bf16x8 __attribute__((ext_vector_type(8)));
typedef float f32x4 __attribute__((ext_vector_type(4)));

__device__ __forceinline__ unsigned short f2bf(float f) {
  union { float f; unsigned u; } v; v.f = f;
  unsigned r = v.u + 0x7fffu + ((v.u >> 16) & 1u);
  return (unsigned short)(r >> 16);
}

// async global->LDS, 16B per lane; LDS dest = wave-uniform base + lane*16
__device__ __forceinline__ void async16(const void* gptr, void* ldsptr) {
  __builtin_amdgcn_global_load_lds(
      (const __attribute__((address_space(1))) unsigned int*)gptr,
      (__attribute__((address_space(3))) unsigned int*)ldsptr,
      16, 0, 0);
}

// =====================================================================
// prep: single fused prologue kernel, role-split by blockIdx.
//  blocks [0, 2048): transpose kernels [M][D][U] f32 -> kT [M][U][D] bf16
//  blocks [2048, 2560): per 16 b-rows: x->bf16, keyv=x@Wk+bk (fp32),
//                        sim -> simT, out init = (1/16) sum_m sim*biases
// =====================================================================
__global__ __launch_bounds__(256) void prep(
    const float* __restrict__ x, const float* __restrict__ key_kernel,
    const float* __restrict__ key_bias, const float* __restrict__ keys_map,
    const float* __restrict__ kernels, const float* __restrict__ biases,
    unsigned short* __restrict__ xb, unsigned short* __restrict__ kT,
    float* __restrict__ simT, float* __restrict__ out) {
  __shared__ float smem[13568];  // 53 KB, aliased per role
  int bid = blockIdx.x;
  int t = threadIdx.x;

  if (bid < 2048) {
    // ---------------- role T: kernels transpose ----------------
    float(*tf)[65] = (float(*)[65])smem;
    int m = bid >> 7;
    int rem = bid & 127;
    int d0 = ((rem >> 3) & 15) * 32, u0 = (rem & 7) * 64;
    {
      int dr = t >> 4, uc = t & 15;
      const float* src = kernels + ((size_t)m * D_SZ + d0 + dr) * U_SZ + u0 + uc * 4;
      float4 a = *(const float4*)src;
      float4 b = *(const float4*)(src + (size_t)16 * U_SZ);
      tf[dr][uc * 4 + 0] = a.x; tf[dr][uc * 4 + 1] = a.y;
      tf[dr][uc * 4 + 2] = a.z; tf[dr][uc * 4 + 3] = a.w;
      tf[dr + 16][uc * 4 + 0] = b.x; tf[dr + 16][uc * 4 + 1] = b.y;
      tf[dr + 16][uc * 4 + 2] = b.z; tf[dr + 16][uc * 4 + 3] = b.w;
    }
    __syncthreads();
    {
      int ur = t >> 2, dc = t & 3;
      unsigned short* dst = kT + ((size_t)m * U_SZ + u0 + ur) * D_SZ + d0 + dc * 8;
      ushort4 lo, hi;
      lo.x = f2bf(tf[dc * 8 + 0][ur]); lo.y = f2bf(tf[dc * 8 + 1][ur]);
      lo.z = f2bf(tf[dc * 8 + 2][ur]); lo.w = f2bf(tf[dc * 8 + 3][ur]);
      hi.x = f2bf(tf[dc * 8 + 4][ur]); hi.y = f2bf(tf[dc * 8 + 5][ur]);
      hi.z = f2bf(tf[dc * 8 + 6][ur]); hi.w = f2bf(tf[dc * 8 + 7][ur]);
      *(ushort4*)dst = lo;
      *(ushort4*)(dst + 4) = hi;
    }
    return;
  }

  // ---------------- role K: 16 b-rows, full row-local pipeline ----------------
  float* xs = smem;             // [16][512]  32 KB
  float* wk = smem + 8192;      // [64][64]   16 KB
  float* kv = smem + 12288;     // [16][64]    4 KB
  float* sims = smem + 13312;   // [16][16]    1 KB
  int b0 = (bid - 2048) * 16;

  // phase 1: stage x rows to LDS (f32) + write bf16 xb
  {
    const float4* xg = (const float4*)(x + (size_t)b0 * D_SZ);
    float4* xs4 = (float4*)xs;
    ushort4* xb4 = (ushort4*)(xb + (size_t)b0 * D_SZ);
#pragma unroll
    for (int p = 0; p < 8; ++p) {
      int idx = p * 256 + t;
      float4 v = xg[idx];
      xs4[idx] = v;
      ushort4 o;
      o.x = f2bf(v.x); o.y = f2bf(v.y); o.z = f2bf(v.z); o.w = f2bf(v.w);
      xb4[idx] = o;
    }
  }

  // phase 2: keyv = x @ key_kernel + key_bias (fp32), Wk chunked via LDS
  int row = t >> 4, kq = t & 15;
  float4 acc = *(const float4*)(key_bias + kq * 4);
  {
    float4* wk4 = (float4*)wk;
    const float4* wg = (const float4*)key_kernel;
    for (int c = 0; c < 8; ++c) {
      __syncthreads();  // covers phase-1 staging on c==0, prior reads after
#pragma unroll
      for (int q = 0; q < 4; ++q) wk4[q * 256 + t] = wg[c * 1024 + q * 256 + t];
      __syncthreads();
      const float* xrow = xs + row * 512 + c * 64;
#pragma unroll 8
      for (int dd = 0; dd < 64; ++dd) {
        float4 kk = wk4[dd * 16 + kq];
        float xv = xrow[dd];
        acc.x += xv * kk.x; acc.y += xv * kk.y;
        acc.z += xv * kk.z; acc.w += xv * kk.w;
      }
    }
  }
  *(float4*)(kv + row * 64 + kq * 4) = acc;
  __syncthreads();

  // phase 3: sim = 1/(dist+1) -> simT global + sims LDS
  {
    int mm = t & 15;  // row = t>>4 as above
    const float* kvr = kv + row * 64;
    const float* km = keys_map + mm * 64;
    float d2 = 0.f;
#pragma unroll 8
    for (int k = 0; k < 64; ++k) {
      float df = kvr[k] - km[k];
      d2 += df * df;
    }
    float s = 1.0f / (sqrtf(d2) + 1.0f);
    simT[(size_t)mm * B_SZ + b0 + row] = s;
    sims[row * 16 + mm] = s;
  }
  __syncthreads();

  // phase 4: out init = (1/16) sum_m sim * biases
  {
    const float4* bg = (const float4*)biases;  // [16][128] float4
    float4* og = (float4*)(out + (size_t)b0 * U_SZ);
#pragma unroll
    for (int p = 0; p < 8; ++p) {
      int idx = p * 256 + t;
      int r2 = idx >> 7, uc = idx & 127;
      float4 a4 = {0.f, 0.f, 0.f, 0.f};
#pragma unroll
      for (int mm = 0; mm < 16; ++mm) {
        float s = sims[r2 * 16 + mm];
        float4 b4 = bg[mm * 128 + uc];
        a4.x += s * b4.x; a4.y += s * b4.y; a4.z += s * b4.z; a4.w += s * b4.w;
      }
      a4.x *= 0.0625f; a4.y *= 0.0625f; a4.z *= 0.0625f; a4.w *= 0.0625f;
      og[idx] = a4;
    }
  }
}

// =====================================================================
// poly_gemm: out[b,u] += (1/16) sum_m sim[b,m] * (x[b,:] @ kernels[m,:,u])
// 512 blocks = 64 bt (128 rows) x 8 ut (64 cols, XCD-pinned via bid&7).
// Flat 128-iter (kt,m) loop, sB double-buffered, ONE barrier per iter,
// B(iter+1) prefetch issued right after the barrier (drain hidden under MFMA).
// A staged per kt (prefetch at m==15); A-frags in registers across 16 modes.
// =====================================================================
__global__ __launch_bounds__(256, 2) void poly_gemm(
    const unsigned short* __restrict__ xb,  // [B][D] bf16
    const unsigned short* __restrict__ kT,  // [M][U][D] bf16
    const float* __restrict__ simT,         // [M][B]
    float* __restrict__ out) {              // [B][U], bias-pre-initialized
  __shared__ unsigned short sA[128 * 64];      // 16 KB
  __shared__ unsigned short sB[2 * 64 * 64];   // 2 x 8 KB

  int t = threadIdx.x, w = t >> 6, l = t & 63;
  int bid = blockIdx.x;
  int ut = bid & 7, bt = bid >> 3;
  int b0 = bt * 128, u0 = ut * 64;

  int rbase = w * 32;  // 4 waves x 32 rows, 64 cols each
  int lane16 = l & 15, quad = l >> 4, sw = lane16 & 7;
  int srow = l >> 3;
  int skk = ((l & 7) ^ srow) * 8;  // swizzled source k-offset (elems)

  const unsigned short* asrc = xb + (size_t)b0 * D_SZ;

  // pre-issue A(kt=0): 16 chunks (4/wave), rows=chunk*8+srow, stride 64
#pragma unroll
  for (int c = 0; c < 4; ++c) {
    int ch = w * 4 + c;
    int row = ch * 8 + srow;
    async16(asrc + (size_t)row * D_SZ + skk, (char*)sA + ch * 1024);
  }
  // pre-issue B(iter=0): m=0, kt=0; 8 chunks (2/wave)
#pragma unroll
  for (int c = 0; c < 2; ++c) {
    int ch = w * 2 + c;
    int row = ch * 8 + srow;
    async16(kT + ((size_t)u0 + row) * D_SZ + skk, (char*)sB + ch * 1024);
  }

  f32x4 facc[2][4];
#pragma unroll
  for (int i = 0; i < 2; ++i)
#pragma unroll
    for (int j = 0; j < 4; ++j) facc[i][j] = (f32x4){0.f, 0.f, 0.f, 0.f};
  bf16x8 af[2][2];

#pragma unroll 1
  for (int iter = 0; iter < 128; ++iter) {
    int kt = iter >> 4, m = iter & 15;
    __syncthreads();  // staging(iter) [+A(kt) if m==0] complete; prior reads done

    int nit = iter + 1;
    if (nit < 128) {  // prefetch B(iter+1) into the other buffer
      int nm = nit & 15, nkt = nit >> 4;
      const unsigned short* bsrc = kT + ((size_t)nm * U_SZ + u0) * D_SZ + nkt * 64;
      char* dst = (char*)sB + (nit & 1) * 8192;
#pragma unroll
      for (int c = 0; c < 2; ++c) {
        int ch = w * 2 + c;
        int row = ch * 8 + srow;
        async16(bsrc + (size_t)row * D_SZ + skk, dst + ch * 1024);
      }
    }
    if (m == 15 && kt < 7) {  // prefetch A(kt+1)
#pragma unroll
      for (int c = 0; c < 4; ++c) {
        int ch = w * 4 + c;
        int row = ch * 8 + srow;
        async16(asrc + (size_t)row * D_SZ + (kt + 1) * 64 + skk,
                (char*)sA + ch * 1024);
      }
    }
    if (m == 0) {  // reload A fragments for this kt
#pragma unroll
      for (int i = 0; i < 2; ++i)
#pragma unroll
        for (int h = 0; h < 2; ++h)
          af[i][h] = *(const bf16x8*)(sA + (size_t)(rbase + i * 16 + lane16) * 64 +
                                      (((h * 4 + quad) ^ sw) * 8));
    }

    const unsigned short* sBc = sB + (iter & 1) * 4096;
    bf16x8 bfr[4][2];
#pragma unroll
    for (int j = 0; j < 4; ++j)
#pragma unroll
      for (int h = 0; h < 2; ++h)
        bfr[j][h] = *(const bf16x8*)(sBc + (size_t)(j * 16 + lane16) * 64 +
                                     (((h * 4 + quad) ^ sw) * 8));

    f32x4 sv[2];
#pragma unroll
    for (int i = 0; i < 2; ++i)
      sv[i] = *(const f32x4*)(simT + (size_t)m * B_SZ + b0 + rbase + i * 16 +
                              quad * 4);

#pragma unroll
    for (int i = 0; i < 2; ++i)
#pragma unroll
      for (int j = 0; j < 4; ++j) {
        f32x4 p = __builtin_amdgcn_mfma_f32_16x16x32_bf16(
            af[i][0], bfr[j][0], (f32x4){0.f, 0.f, 0.f, 0.f}, 0, 0, 0);
        p = __builtin_amdgcn_mfma_f32_16x16x32_bf16(af[i][1], bfr[j][1], p, 0, 0, 0);
#pragma unroll
        for (int r = 0; r < 4; ++r) facc[i][j][r] += sv[i][r] * p[r];
      }
  }

  // epilogue: RMW-add onto bias-initialized out
#pragma unroll
  for (int i = 0; i < 2; ++i)
#pragma unroll
    for (int r = 0; r < 4; ++r) {
      int row = b0 + rbase + i * 16 + quad * 4 + r;
      float* orow = out + (size_t)row * U_SZ + u0;
#pragma unroll
      for (int j = 0; j < 4; ++j)
        orow[j * 16 + lane16] += facc[i][j][r] * 0.0625f;
    }
}

extern "C" void kernel_launch(void* const* d_in, const int* in_sizes, int n_in,
                              void* d_out, int out_size, void* d_ws, size_t ws_size,
                              hipStream_t stream) {
  const float* x = (const float*)d_in[0];
  const float* key_kernel = (const float*)d_in[1];
  const float* key_bias = (const float*)d_in[2];
  const float* keys_map = (const float*)d_in[3];
  const float* kernels = (const float*)d_in[4];
  const float* biases = (const float*)d_in[5];
  float* out = (float*)d_out;

  // ws: xb 8MB | kT 8.4MB | simT 512KB
  char* p = (char*)d_ws;
  unsigned short* xb = (unsigned short*)p;  p += (size_t)B_SZ * D_SZ * 2;
  unsigned short* kT = (unsigned short*)p;  p += (size_t)M_SZ * U_SZ * D_SZ * 2;
  float* simT = (float*)p;

  prep<<<dim3(2560), 256, 0, stream>>>(x, key_kernel, key_bias, keys_map,
                                       kernels, biases, xb, kT, simT, out);
  poly_gemm<<<dim3(512), 256, 0, stream>>>(xb, kT, simT, out);
}

// Round 6
// 172.574 us; speedup vs baseline: 1.3571x; 1.3571x over previous
//
#include <hip/hip_runtime.h>
#include <hip/hip_bf16.h>
#include <stdint.h>

#define B_SZ 8192
#define D_SZ 512
#define U_SZ 512
#define M_SZ 16
#define K_SZ 64

typedef short bf16x8 __attribute__((ext_vector_type(8)));
typedef float f32x4 __attribute__((ext_vector_type(4)));

__device__ __forceinline__ unsigned short f2bf(float f) {
  union { float f; unsigned u; } v; v.f = f;
  unsigned r = v.u + 0x7fffu + ((v.u >> 16) & 1u);
  return (unsigned short)(r >> 16);
}

// =====================================================================
// prep1: role-split single launch. ALL outputs are fragment-linear bf16.
//  [0,2048):    kernels [M][D][U] f32 -> kbf [m][ut][kt][j][h][lane][8]
//  [2048,2056): key_kernel [D][K]     -> wkbf [kt][j][h][lane][8]
//  [2056,2568): x [B][D]              -> xbf [bt][kt][i][h][lane][8]
// lane = quad*16+lane16; elem e = k offset kt*64 + h*32 + quad*8 + e.
// =====================================================================
__global__ __launch_bounds__(256) void prep1(
    const float* __restrict__ x, const float* __restrict__ key_kernel,
    const float* __restrict__ kernels, unsigned short* __restrict__ xbf,
    unsigned short* __restrict__ kbf, unsigned short* __restrict__ wkbf) {
  __shared__ float tf[32][65];
  int bid = blockIdx.x;
  int t = threadIdx.x;

  if (bid < 2048) {
    // ---- role T: kernels -> kbf (frag-linear B operand) ----
    int m = bid >> 7;
    int rem = bid & 127;
    int a = (rem >> 3) & 15;  // d-tile (32 d's)
    int ut = rem & 7;         // u-tile (64 u's)
    int d0 = a * 32, u0 = ut * 64;
    {
      int dr = t >> 4, uc = t & 15;
      const float* src = kernels + ((size_t)m * D_SZ + d0 + dr) * U_SZ + u0 + uc * 4;
      float4 aa = *(const float4*)src;
      float4 bb = *(const float4*)(src + (size_t)16 * U_SZ);
      tf[dr][uc * 4 + 0] = aa.x; tf[dr][uc * 4 + 1] = aa.y;
      tf[dr][uc * 4 + 2] = aa.z; tf[dr][uc * 4 + 3] = aa.w;
      tf[dr + 16][uc * 4 + 0] = bb.x; tf[dr + 16][uc * 4 + 1] = bb.y;
      tf[dr + 16][uc * 4 + 2] = bb.z; tf[dr + 16][uc * 4 + 3] = bb.w;
    }
    __syncthreads();
    {
      int ur = t >> 2, dc = t & 3;  // u-row 0..63, d-oct 0..3
      int j = ur >> 4, lane16 = ur & 15;
      int kt = a >> 1, h = a & 1;   // quad == dc (d0 multiple of 32)
      unsigned short* dst = kbf +
          (((((size_t)m * 8 + ut) * 8 + kt) * 4 + j) * 2 + h) * 512 +
          ((size_t)dc * 16 + lane16) * 8;
      ushort4 lo, hi;
      lo.x = f2bf(tf[dc * 8 + 0][ur]); lo.y = f2bf(tf[dc * 8 + 1][ur]);
      lo.z = f2bf(tf[dc * 8 + 2][ur]); lo.w = f2bf(tf[dc * 8 + 3][ur]);
      hi.x = f2bf(tf[dc * 8 + 4][ur]); hi.y = f2bf(tf[dc * 8 + 5][ur]);
      hi.z = f2bf(tf[dc * 8 + 6][ur]); hi.w = f2bf(tf[dc * 8 + 7][ur]);
      *(ushort4*)dst = lo;
      *(ushort4*)(dst + 4) = hi;
    }
    return;
  }

  if (bid < 2056) {
    // ---- role W: key_kernel -> wkbf ----
    int kt = bid - 2048;
#pragma unroll
    for (int rep = 0; rep < 2; ++rep) {
      int c = rep * 256 + t;
      int j = c >> 7, h = (c >> 6) & 1, quad = (c >> 4) & 3, ln = c & 15;
      int dd = kt * 64 + h * 32 + quad * 8;
      int u = j * 16 + ln;
      unsigned short v[8];
#pragma unroll
      for (int e = 0; e < 8; ++e)
        v[e] = f2bf(key_kernel[(size_t)(dd + e) * K_SZ + u]);
      unsigned short* dst =
          wkbf + ((size_t)((kt * 4 + j) * 2 + h) * 64 + quad * 16 + ln) * 8;
#pragma unroll
      for (int e = 0; e < 8; ++e) dst[e] = v[e];
    }
    return;
  }

  // ---- role X: x -> xbf (frag-linear A operand) ----
  int xb0 = bid - 2056;
  int bt = xb0 >> 3, i = xb0 & 7;
  int b0 = xb0 * 16;
#pragma unroll
  for (int rep = 0; rep < 4; ++rep) {
    int idx = rep * 256 + t;
    int kt = idx >> 7, h = (idx >> 6) & 1, quad = (idx >> 4) & 3, ln = idx & 15;
    const float* src = x + (size_t)(b0 + ln) * D_SZ + kt * 64 + h * 32 + quad * 8;
    float4 a = *(const float4*)src;
    float4 b = *(const float4*)(src + 4);
    ushort4 lo, hi;
    lo.x = f2bf(a.x); lo.y = f2bf(a.y); lo.z = f2bf(a.z); lo.w = f2bf(a.w);
    hi.x = f2bf(b.x); hi.y = f2bf(b.y); hi.z = f2bf(b.z); hi.w = f2bf(b.w);
    unsigned short* dst =
        xbf + ((((size_t)bt * 8 + kt) * 8 + i) * 2 + h) * 512 +
        ((size_t)quad * 16 + ln) * 8;
    *(ushort4*)dst = lo;
    *(ushort4*)(dst + 4) = hi;
  }
}

// =====================================================================
// prep2: keyv = xb @ Wk + bias (MFMA, frags direct from global), then sim.
// 128 blocks x 64 rows. No LDS in GEMM loop; one barrier before sim phase.
// =====================================================================
__global__ __launch_bounds__(256) void prep2(
    const unsigned short* __restrict__ xbf, const unsigned short* __restrict__ wkbf,
    const float* __restrict__ key_bias, const float* __restrict__ keys_map,
    float* __restrict__ simT) {
  __shared__ float kv[64][68];
  __shared__ float sKM[16][64];
  int t = threadIdx.x, w = t >> 6, l = t & 63;
  int blk = blockIdx.x;
  int b0 = blk * 64, bt = blk >> 1, ibase = (blk & 1) * 4;
  int lane16 = l & 15, quad = l >> 4;

  ((float4*)sKM)[t] = ((const float4*)keys_map)[t];

  f32x4 acc[4];
#pragma unroll
  for (int j = 0; j < 4; ++j) acc[j] = (f32x4){0.f, 0.f, 0.f, 0.f};

  for (int kt = 0; kt < 8; ++kt) {
    bf16x8 af[2];
#pragma unroll
    for (int h = 0; h < 2; ++h)
      af[h] = *(const bf16x8*)(xbf +
                               ((((size_t)bt * 8 + kt) * 8 + ibase + w) * 2 + h) * 512 +
                               (size_t)l * 8);
#pragma unroll
    for (int j = 0; j < 4; ++j) {
      bf16x8 b0f = *(const bf16x8*)(wkbf + ((size_t)((kt * 4 + j) * 2 + 0) * 64 + l) * 8);
      bf16x8 b1f = *(const bf16x8*)(wkbf + ((size_t)((kt * 4 + j) * 2 + 1) * 64 + l) * 8);
      acc[j] = __builtin_amdgcn_mfma_f32_16x16x32_bf16(af[0], b0f, acc[j], 0, 0, 0);
      acc[j] = __builtin_amdgcn_mfma_f32_16x16x32_bf16(af[1], b1f, acc[j], 0, 0, 0);
    }
  }
#pragma unroll
  for (int j = 0; j < 4; ++j) {
    float bc = key_bias[j * 16 + lane16];
#pragma unroll
    for (int r = 0; r < 4; ++r)
      kv[w * 16 + quad * 4 + r][j * 16 + lane16] = acc[j][r] + bc;
  }
  __syncthreads();

  int row = t >> 2, mg = (t & 3) * 4;
  float d2[4] = {0.f, 0.f, 0.f, 0.f};
#pragma unroll 8
  for (int k = 0; k < 64; ++k) {
    float kvv = kv[row][k];
#pragma unroll
    for (int q = 0; q < 4; ++q) {
      float df = kvv - sKM[mg + q][k];
      d2[q] += df * df;
    }
  }
#pragma unroll
  for (int q = 0; q < 4; ++q)
    simT[(size_t)(mg + q) * B_SZ + b0 + row] = 1.0f / (sqrtf(d2[q]) + 1.0f);
}

// =====================================================================
// poly_gemm: out[b,u] = (1/16) sum_m sim[b,m]*(x@kernels_m + biases_m)
// 512 blocks = 64 bt (128 rows) x 8 ut (64 cols, ut==bid&7 -> XCD-pinned:
// each 1MB kbf mode-slice stays in one XCD's L2).
// Waves: half = w>>1 (modes 0-7 / 8-15), rw = w&1 (64-row half).
// MAIN LOOP HAS NO LDS AND NO BARRIERS: A and B fragments load directly
// global->VGPR from fragment-linear xbf/kbf (race-free by construction).
// LDS only for the 2-barrier epilogue half-combine.
// =====================================================================
__global__ __launch_bounds__(256, 2) void poly_gemm(
    const unsigned short* __restrict__ xbf,  // A frag-linear
    const unsigned short* __restrict__ kbf,  // B frag-linear
    const float* __restrict__ simT,          // [M][B]
    const float* __restrict__ biases,        // [M][U] f32
    float* __restrict__ out) {               // [B][U]
  __shared__ float sRed[8192];  // 32 KB, epilogue only

  int t = threadIdx.x, w = t >> 6, l = t & 63;
  int bid = blockIdx.x;
  int ut = bid & 7, bt = bid >> 3;
  int b0 = bt * 128, u0 = ut * 64;
  int half = w >> 1, rw = w & 1;
  int lane16 = l & 15, quad = l >> 4;

  f32x4 facc[4][4];
#pragma unroll
  for (int i = 0; i < 4; ++i)
#pragma unroll
    for (int j = 0; j < 4; ++j) facc[i][j] = (f32x4){0.f, 0.f, 0.f, 0.f};

#pragma unroll 1
  for (int kt = 0; kt < 8; ++kt) {
    bf16x8 af[4][2];
#pragma unroll
    for (int ii = 0; ii < 4; ++ii)
#pragma unroll
      for (int h = 0; h < 2; ++h)
        af[ii][h] = *(const bf16x8*)(
            xbf + ((((size_t)bt * 8 + kt) * 8 + rw * 4 + ii) * 2 + h) * 512 +
            (size_t)l * 8);

#pragma unroll 2
    for (int mi = 0; mi < 8; ++mi) {
      int mode = half * 8 + mi;
      const unsigned short* bb =
          kbf + ((((size_t)mode * 8 + ut) * 8 + kt) * 4) * 2 * 512;
      bf16x8 bfr[4][2];
#pragma unroll
      for (int j = 0; j < 4; ++j)
#pragma unroll
        for (int h = 0; h < 2; ++h)
          bfr[j][h] = *(const bf16x8*)(bb + ((size_t)(j * 2 + h)) * 512 +
                                       (size_t)l * 8);

      f32x4 sv[4];
#pragma unroll
      for (int i = 0; i < 4; ++i)
        sv[i] = *(const f32x4*)(simT + (size_t)mode * B_SZ + b0 + rw * 64 +
                                i * 16 + quad * 4);

#pragma unroll
      for (int i = 0; i < 4; ++i)
#pragma unroll
        for (int j = 0; j < 4; ++j) {
          f32x4 p = __builtin_amdgcn_mfma_f32_16x16x32_bf16(
              af[i][0], bfr[j][0], (f32x4){0.f, 0.f, 0.f, 0.f}, 0, 0, 0);
          p = __builtin_amdgcn_mfma_f32_16x16x32_bf16(af[i][1], bfr[j][1], p,
                                                      0, 0, 0);
#pragma unroll
          for (int r = 0; r < 4; ++r) facc[i][j][r] += sv[i][r] * p[r];
        }

      if (kt == 0) {  // bias term, once per mode
        float bbv[4];
#pragma unroll
        for (int j = 0; j < 4; ++j)
          bbv[j] = biases[(size_t)mode * U_SZ + u0 + j * 16 + lane16];
#pragma unroll
        for (int i = 0; i < 4; ++i)
#pragma unroll
          for (int j = 0; j < 4; ++j)
#pragma unroll
            for (int r = 0; r < 4; ++r) facc[i][j][r] += sv[i][r] * bbv[j];
      }
    }
  }

  // epilogue: combine mode-halves via LDS (the only barriers in the kernel)
  __syncthreads();
  if (half == 1) {
#pragma unroll
    for (int i = 0; i < 4; ++i)
#pragma unroll
      for (int r = 0; r < 4; ++r)
#pragma unroll
        for (int j = 0; j < 4; ++j)
          sRed[rw * 4096 + (i * 16 + quad * 4 + r) * 64 + j * 16 + lane16] =
              facc[i][j][r];
  }
  __syncthreads();
  if (half == 0) {
#pragma unroll
    for (int i = 0; i < 4; ++i)
#pragma unroll
      for (int r = 0; r < 4; ++r) {
        int row = b0 + rw * 64 + i * 16 + quad * 4 + r;
        float* orow = out + (size_t)row * U_SZ + u0;
#pragma unroll
        for (int j = 0; j < 4; ++j)
          orow[j * 16 + lane16] =
              (facc[i][j][r] +
               sRed[rw * 4096 + (i * 16 + quad * 4 + r) * 64 + j * 16 + lane16]) *
              0.0625f;
      }
  }
}

extern "C" void kernel_launch(void* const* d_in, const int* in_sizes, int n_in,
                              void* d_out, int out_size, void* d_ws, size_t ws_size,
                              hipStream_t stream) {
  const float* x = (const float*)d_in[0];
  const float* key_kernel = (const float*)d_in[1];
  const float* key_bias = (const float*)d_in[2];
  const float* keys_map = (const float*)d_in[3];
  const float* kernels = (const float*)d_in[4];
  const float* biases = (const float*)d_in[5];
  float* out = (float*)d_out;

  // ws: xbf 8MB | kbf 8MB | wkbf 64KB | simT 512KB
  char* p = (char*)d_ws;
  unsigned short* xbf = (unsigned short*)p;  p += (size_t)B_SZ * D_SZ * 2;
  unsigned short* kbf = (unsigned short*)p;  p += (size_t)M_SZ * U_SZ * D_SZ * 2;
  unsigned short* wkbf = (unsigned short*)p; p += (size_t)K_SZ * D_SZ * 2;
  float* simT = (float*)p;

  prep1<<<dim3(2568), 256, 0, stream>>>(x, key_kernel, kernels, xbf, kbf, wkbf);
  prep2<<<dim3(128), 256, 0, stream>>>(xbf, wkbf, key_bias, keys_map, simT);
  poly_gemm<<<dim3(512), 256, 0, stream>>>(xbf, kbf, simT, biases, out);
}